// Round 2
// baseline (970.637 us; speedup 1.0000x reference)
//
#include <hip/hip_runtime.h>
#include <hip/hip_bf16.h>

typedef __bf16 bf16x8 __attribute__((ext_vector_type(8)));
typedef __bf16 bf16x4 __attribute__((ext_vector_type(4)));
typedef float  f32x4  __attribute__((ext_vector_type(4)));

// ---------------- cast fp32 -> bf16, 8 elems/thread ----------------
__global__ void cast_f32_bf16(const float* __restrict__ src, __bf16* __restrict__ dst, int n8) {
    int i = blockIdx.x * 256 + threadIdx.x;
    if (i >= n8) return;
    const float4* s = (const float4*)src;
    float4 a = s[2 * i], b = s[2 * i + 1];
    bf16x8 o;
    o[0] = (__bf16)a.x; o[1] = (__bf16)a.y; o[2] = (__bf16)a.z; o[3] = (__bf16)a.w;
    o[4] = (__bf16)b.x; o[5] = (__bf16)b.y; o[6] = (__bf16)b.z; o[7] = (__bf16)b.w;
    ((bf16x8*)dst)[i] = o;
}

// ---------------- GEMM: C[M][N] = A[M][K] * Bm[N][K]^T (bf16 in, bf16/f32 out) ----
template <int OUT_BF16>
__global__ __launch_bounds__(256)
void gemm_bt(const __bf16* __restrict__ A, const __bf16* __restrict__ Bm,
             void* __restrict__ Cout, int M, int N, int K) {
    __shared__ __bf16 As[128 * 64];
    __shared__ __bf16 Bs[128 * 64];
    const int tid = threadIdx.x;
    const int lane = tid & 63, wid = tid >> 6;
    const int g = lane >> 4, lq = lane & 15;
    const int wr = wid >> 1, wc = wid & 1;
    const size_t brow = (size_t)blockIdx.y * 128, bcol = (size_t)blockIdx.x * 128;
    f32x4 acc[4][4] = {};
    const int nkt = K >> 6;

    for (int kt = 0; kt < nkt; ++kt) {
        __syncthreads();
#pragma unroll
        for (int is = 0; is < 4; ++is) {
            int flat = is * 4096 + tid * 16;       // bytes within 16KB tile
            int row  = flat >> 7;                  // 128B per row (64 bf16)
            int colb = flat & 127;
            int sw   = colb ^ ((row & 7) << 4);
            int4 va = *(const int4*)((const char*)A + ((brow + row) * (size_t)K + (size_t)kt * 64) * 2 + colb);
            *(int4*)((char*)As + row * 128 + sw) = va;
            int4 vb = *(const int4*)((const char*)Bm + ((bcol + row) * (size_t)K + (size_t)kt * 64) * 2 + colb);
            *(int4*)((char*)Bs + row * 128 + sw) = vb;
        }
        __syncthreads();
#pragma unroll
        for (int ks = 0; ks < 2; ++ks) {
            bf16x8 af[4], bfr[4];
            const int kb = ks * 64 + g * 16;
#pragma unroll
            for (int i = 0; i < 4; ++i) {
                int row = wr * 64 + i * 16 + lq;
                af[i] = *(const bf16x8*)((const char*)As + row * 128 + (kb ^ ((row & 7) << 4)));
            }
#pragma unroll
            for (int j = 0; j < 4; ++j) {
                int row = wc * 64 + j * 16 + lq;
                bfr[j] = *(const bf16x8*)((const char*)Bs + row * 128 + (kb ^ ((row & 7) << 4)));
            }
#pragma unroll
            for (int i = 0; i < 4; ++i)
#pragma unroll
                for (int j = 0; j < 4; ++j)
                    acc[i][j] = __builtin_amdgcn_mfma_f32_16x16x32_bf16(af[i], bfr[j], acc[i][j], 0, 0, 0);
        }
    }
#pragma unroll
    for (int i = 0; i < 4; ++i) {
#pragma unroll
        for (int r = 0; r < 4; ++r) {
            size_t row = brow + wr * 64 + i * 16 + g * 4 + r;
#pragma unroll
            for (int j = 0; j < 4; ++j) {
                size_t col = bcol + wc * 64 + j * 16 + lq;
                float v = acc[i][j][r];
                if (OUT_BF16) ((__bf16*)Cout)[row * N + col] = (__bf16)v;
                else          ((float*)Cout)[row * N + col] = v;
            }
        }
    }
}

// ---------------- V transpose: qkv V-part -> vt[(b*8+kh)*128+d][t] ----------------
__global__ __launch_bounds__(256)
void transpose_v(const __bf16* __restrict__ qkv, __bf16* __restrict__ vt) {
    constexpr int S = 2048, QKVN = 6144;
    __shared__ __bf16 tile[64][72];
    const int tt = blockIdx.x;
    const int yz = blockIdx.y;
    const int dh = yz & 1, bkh = yz >> 1;
    const int b = bkh >> 3, kh = bkh & 7;
    const int tid = threadIdx.x;
#pragma unroll
    for (int i = 0; i < 2; ++i) {
        int flat = i * 2048 + tid * 8;
        int r = flat >> 6, c0 = flat & 63;
        const __bf16* src = qkv + ((size_t)b * S + tt * 64 + r) * QKVN + 5120 + kh * 128 + dh * 64 + c0;
        *(bf16x8*)&tile[r][c0] = *(const bf16x8*)src;
    }
    __syncthreads();
#pragma unroll
    for (int i = 0; i < 2; ++i) {
        int flat = i * 2048 + tid * 8;
        int d = flat >> 6, t0 = flat & 63;
        bf16x8 pk;
#pragma unroll
        for (int e = 0; e < 8; ++e) pk[e] = tile[t0 + e][d];
        __bf16* dst = vt + ((size_t)(b * 8 + kh) * 128 + dh * 64 + d) * S + tt * 64 + t0;
        *(bf16x8*)dst = pk;
    }
}

// ---------------- flash attention (causal, GQA) ----------------
// 128 q-rows/block, 4 waves x 32 rows (two 16-row frags). KVBLK=64.
// Swapped QK^T (mfma(K,Q)): lane lq owns q-row; softmax lane-local + 2 shfl_xor.
// T14: next K/V tile prefetched into regs during compute.

__device__ __forceinline__ void softmax_step(
    f32x4 sc[4], float& m_r, float& l_r, f32x4 acc[8],
    __bf16* psrow, int kt, int qg, bool domask, int g, int lq)
{
    const float scale = 0.088388347648318447f;   // 1/sqrt(128)
    float p[4][4];
    float rowmax = -1e30f;
#pragma unroll
    for (int tb = 0; tb < 4; ++tb)
#pragma unroll
        for (int r = 0; r < 4; ++r) {
            float sv = sc[tb][r] * scale;
            if (domask) {
                int tg = kt * 64 + tb * 16 + g * 4 + r;
                sv = (tg <= qg) ? sv : -1e30f;
            }
            p[tb][r] = sv;
            rowmax = fmaxf(rowmax, sv);
        }
    rowmax = fmaxf(rowmax, __shfl_xor(rowmax, 16));
    rowmax = fmaxf(rowmax, __shfl_xor(rowmax, 32));
    float m_new = fmaxf(m_r, rowmax);
    float alpha = __expf(m_r - m_new);
    float rowsum = 0.f;
#pragma unroll
    for (int tb = 0; tb < 4; ++tb)
#pragma unroll
        for (int r = 0; r < 4; ++r) {
            float e = __expf(p[tb][r] - m_new);
            p[tb][r] = e;
            rowsum += e;
        }
    rowsum += __shfl_xor(rowsum, 16);
    rowsum += __shfl_xor(rowsum, 32);
    l_r = l_r * alpha + rowsum;
    m_r = m_new;
#pragma unroll
    for (int r = 0; r < 4; ++r) {
        float ar = __shfl(alpha, g * 4 + r);
#pragma unroll
        for (int nb = 0; nb < 8; ++nb) acc[nb][r] *= ar;
    }
#pragma unroll
    for (int tb = 0; tb < 4; ++tb) {
        bf16x4 pkv;
#pragma unroll
        for (int r = 0; r < 4; ++r) pkv[r] = (__bf16)p[tb][r];
        *(bf16x4*)((char*)psrow + lq * 144 + (tb * 16 + g * 4) * 2) = pkv;
    }
}

__global__ __launch_bounds__(256)
void attn_kernel(const __bf16* __restrict__ qkv, const __bf16* __restrict__ vt,
                 __bf16* __restrict__ outb) {
    constexpr int S = 2048, D = 128, QKVN = 6144;
    const int qt = (int)(gridDim.x - 1) - (int)blockIdx.x;   // heavy blocks first
    const int bh = blockIdx.y;
    const int b = bh >> 5, h = bh & 31;
    const int kh = h >> 2;
    const int tid = threadIdx.x, lane = tid & 63, w = tid >> 6;
    const int g = lane >> 4, lq = lane & 15;

    __shared__ __bf16 Ks[64 * 128];      // [t][d], rows 256B, XOR-swizzled
    __shared__ __bf16 Vs[128 * 64];      // [d][t], rows 128B, XOR-swizzled
    __shared__ __bf16 Ps[4][2][1152];    // per-wave, per-frag P; row stride 144B

    const int wqmin = qt * 128 + w * 32;
    const int wqmax = wqmin + 31;
    const int qg0 = wqmin + lq;
    const int qg1 = qg0 + 16;

    // Q fragments for both 16-row frags (L2-resident reads)
    const __bf16* qrow0 = qkv + ((size_t)(b * S) + wqmin + lq) * QKVN + h * D;
    bf16x8 qf0[4], qf1[4];
#pragma unroll
    for (int ks = 0; ks < 4; ++ks) {
        qf0[ks] = *(const bf16x8*)(qrow0 + ks * 32 + g * 8);
        qf1[ks] = *(const bf16x8*)(qrow0 + (size_t)16 * QKVN + ks * 32 + g * 8);
    }

    const char* kbase = (const char*)qkv + ((size_t)(b * S) * QKVN + 4096 + kh * D) * 2;
    const char* vbase = (const char*)vt + ((size_t)(b * 8 + kh) * D * S) * 2;

    f32x4 acc0[8] = {}, acc1[8] = {};
    float m0 = -1e30f, l0 = 0.f, m1 = -1e30f, l1 = 0.f;

    const int ktmax = 2 * qt + 1;
    int4 pk[4], pv[4];
    // prologue: prefetch tile 0
#pragma unroll
    for (int is = 0; is < 4; ++is) {
        pk[is] = *(const int4*)(kbase + ((size_t)(is * 16 + (tid >> 4)) * QKVN) * 2 + (tid & 15) * 16);
        pv[is] = *(const int4*)(vbase + ((size_t)(is * 32 + (tid >> 3)) * S) * 2 + (tid & 7) * 16);
    }

    for (int kt = 0; kt <= ktmax; ++kt) {
        __syncthreads();                       // everyone done reading previous tile
        // write prefetched tile to LDS (swizzled)
#pragma unroll
        for (int is = 0; is < 4; ++is) {
            int row = is * 16 + (tid >> 4), colb = (tid & 15) * 16;
            *(int4*)((char*)Ks + row * 256 + (colb ^ ((row & 7) << 4))) = pk[is];
            int d = is * 32 + (tid >> 3), cvb = (tid & 7) * 16;
            *(int4*)((char*)Vs + d * 128 + (cvb ^ ((d & 7) << 4))) = pv[is];
        }
        if (kt < ktmax) {                      // prefetch next tile (overlaps compute)
#pragma unroll
            for (int is = 0; is < 4; ++is) {
                pk[is] = *(const int4*)(kbase + ((size_t)((kt + 1) * 64 + is * 16 + (tid >> 4)) * QKVN) * 2 + (tid & 15) * 16);
                pv[is] = *(const int4*)(vbase + ((size_t)(is * 32 + (tid >> 3)) * S + (kt + 1) * 64) * 2 + (tid & 7) * 16);
            }
        }
        __syncthreads();                       // tile ready

        if (kt * 64 <= wqmax) {
            const bool domask = (kt * 64 + 63 > wqmin);
            f32x4 sc0[4], sc1[4];
#pragma unroll
            for (int tb = 0; tb < 4; ++tb) {
                f32x4 s0 = {0.f, 0.f, 0.f, 0.f}, s1 = {0.f, 0.f, 0.f, 0.f};
                const int trow = tb * 16 + lq;
                const int rsw = (trow & 7) << 4;
#pragma unroll
                for (int ks = 0; ks < 4; ++ks) {
                    bf16x8 kf = *(const bf16x8*)((const char*)Ks + trow * 256 + ((ks * 64 + g * 16) ^ rsw));
                    s0 = __builtin_amdgcn_mfma_f32_16x16x32_bf16(kf, qf0[ks], s0, 0, 0, 0);
                    s1 = __builtin_amdgcn_mfma_f32_16x16x32_bf16(kf, qf1[ks], s1, 0, 0, 0);
                }
                sc0[tb] = s0; sc1[tb] = s1;
            }
            softmax_step(sc0, m0, l0, acc0, &Ps[w][0][0], kt, qg0, domask, g, lq);
            softmax_step(sc1, m1, l1, acc1, &Ps[w][1][0], kt, qg1, domask, g, lq);
#pragma unroll
            for (int ks = 0; ks < 2; ++ks) {
                bf16x8 pa0 = *(const bf16x8*)((const char*)&Ps[w][0][0] + lq * 144 + ks * 64 + g * 16);
                bf16x8 pa1 = *(const bf16x8*)((const char*)&Ps[w][1][0] + lq * 144 + ks * 64 + g * 16);
#pragma unroll
                for (int nb = 0; nb < 8; ++nb) {
                    int d = nb * 16 + lq;
                    bf16x8 vf = *(const bf16x8*)((const char*)Vs + d * 128 + ((ks * 64 + g * 16) ^ ((d & 7) << 4)));
                    acc0[nb] = __builtin_amdgcn_mfma_f32_16x16x32_bf16(pa0, vf, acc0[nb], 0, 0, 0);
                    acc1[nb] = __builtin_amdgcn_mfma_f32_16x16x32_bf16(pa1, vf, acc1[nb], 0, 0, 0);
                }
            }
        }
    }

    // epilogue
    float rl0 = 1.f / l0, rl1 = 1.f / l1;
#pragma unroll
    for (int r = 0; r < 4; ++r) {
        float rr0 = __shfl(rl0, g * 4 + r);
        float rr1 = __shfl(rl1, g * 4 + r);
        size_t row0 = (size_t)(b * S) + wqmin + g * 4 + r;
        __bf16* orow0 = outb + row0 * 4096 + h * D;
        __bf16* orow1 = orow0 + (size_t)16 * 4096;
#pragma unroll
        for (int nb = 0; nb < 8; ++nb) {
            orow0[nb * 16 + lq] = (__bf16)(acc0[nb][r] * rr0);
            orow1[nb * 16 + lq] = (__bf16)(acc1[nb][r] * rr1);
        }
    }
}

// ---------------- launch ----------------
extern "C" void kernel_launch(void* const* d_in, const int* in_sizes, int n_in,
                              void* d_out, int out_size, void* d_ws, size_t ws_size,
                              hipStream_t stream) {
    (void)in_sizes; (void)n_in; (void)out_size; (void)ws_size;
    const float* q       = (const float*)d_in[0];
    const float* w_qkv   = (const float*)d_in[1];
    const float* w_dense = (const float*)d_in[2];
    float* out = (float*)d_out;
    char* ws = (char*)d_ws;

    __bf16* qbf      = (__bf16*)(ws);
    __bf16* wqkvbf   = (__bf16*)(ws + 33554432ULL);
    __bf16* wdensebf = (__bf16*)(ws + 83886080ULL);
    __bf16* qkvbf    = (__bf16*)(ws + 117440512ULL);
    __bf16* vtbf     = (__bf16*)(ws + 167772160ULL);
    __bf16* attnbf   = (__bf16*)(ws + 176160768ULL);

    cast_f32_bf16<<<8192, 256, 0, stream>>>(q, qbf, 2097152);
    cast_f32_bf16<<<12288, 256, 0, stream>>>(w_qkv, wqkvbf, 3145728);
    cast_f32_bf16<<<8192, 256, 0, stream>>>(w_dense, wdensebf, 2097152);

    gemm_bt<1><<<dim3(48, 32), 256, 0, stream>>>(qbf, wqkvbf, (void*)qkvbf, 4096, 6144, 4096);
    transpose_v<<<dim3(32, 32), 256, 0, stream>>>(qkvbf, vtbf);
    attn_kernel<<<dim3(16, 64), 256, 0, stream>>>(qkvbf, vtbf, attnbf);
    gemm_bt<0><<<dim3(32, 32), 256, 0, stream>>>(attnbf, wdensebf, (void*)out, 4096, 4096, 4096);
}

// Round 3
// 842.784 us; speedup vs baseline: 1.1517x; 1.1517x over previous
//
#include <hip/hip_runtime.h>
#include <hip/hip_bf16.h>

typedef __bf16 bf16x8 __attribute__((ext_vector_type(8)));
typedef __bf16 bf16x4 __attribute__((ext_vector_type(4)));
typedef float  f32x4  __attribute__((ext_vector_type(4)));

// ---------------- cast fp32 -> bf16, 8 elems/thread ----------------
__global__ void cast_f32_bf16(const float* __restrict__ src, __bf16* __restrict__ dst, int n8) {
    int i = blockIdx.x * 256 + threadIdx.x;
    if (i >= n8) return;
    const float4* s = (const float4*)src;
    float4 a = s[2 * i], b = s[2 * i + 1];
    bf16x8 o;
    o[0] = (__bf16)a.x; o[1] = (__bf16)a.y; o[2] = (__bf16)a.z; o[3] = (__bf16)a.w;
    o[4] = (__bf16)b.x; o[5] = (__bf16)b.y; o[6] = (__bf16)b.z; o[7] = (__bf16)b.w;
    ((bf16x8*)dst)[i] = o;
}

// ---------------- GEMM: C[M][N] = A[M][K] * Bm[N][K]^T ----------------
template <int OUT_BF16>
__global__ __launch_bounds__(256)
void gemm_bt(const __bf16* __restrict__ A, const __bf16* __restrict__ Bm,
             void* __restrict__ Cout, int M, int N, int K) {
    __shared__ __bf16 As[128 * 64];
    __shared__ __bf16 Bs[128 * 64];
    const int tid = threadIdx.x;
    const int lane = tid & 63, wid = tid >> 6;
    const int g = lane >> 4, lq = lane & 15;
    const int wr = wid >> 1, wc = wid & 1;
    const size_t brow = (size_t)blockIdx.y * 128, bcol = (size_t)blockIdx.x * 128;
    f32x4 acc[4][4] = {};
    const int nkt = K >> 6;

    for (int kt = 0; kt < nkt; ++kt) {
        __syncthreads();
#pragma unroll
        for (int is = 0; is < 4; ++is) {
            int flat = is * 4096 + tid * 16;
            int row  = flat >> 7;
            int colb = flat & 127;
            int sw   = colb ^ ((row & 7) << 4);
            int4 va = *(const int4*)((const char*)A + ((brow + row) * (size_t)K + (size_t)kt * 64) * 2 + colb);
            *(int4*)((char*)As + row * 128 + sw) = va;
            int4 vb = *(const int4*)((const char*)Bm + ((bcol + row) * (size_t)K + (size_t)kt * 64) * 2 + colb);
            *(int4*)((char*)Bs + row * 128 + sw) = vb;
        }
        __syncthreads();
#pragma unroll
        for (int ks = 0; ks < 2; ++ks) {
            bf16x8 af[4], bfr[4];
            const int kb = ks * 64 + g * 16;
#pragma unroll
            for (int i = 0; i < 4; ++i) {
                int row = wr * 64 + i * 16 + lq;
                af[i] = *(const bf16x8*)((const char*)As + row * 128 + (kb ^ ((row & 7) << 4)));
            }
#pragma unroll
            for (int j = 0; j < 4; ++j) {
                int row = wc * 64 + j * 16 + lq;
                bfr[j] = *(const bf16x8*)((const char*)Bs + row * 128 + (kb ^ ((row & 7) << 4)));
            }
#pragma unroll
            for (int i = 0; i < 4; ++i)
#pragma unroll
                for (int j = 0; j < 4; ++j)
                    acc[i][j] = __builtin_amdgcn_mfma_f32_16x16x32_bf16(af[i], bfr[j], acc[i][j], 0, 0, 0);
        }
    }
#pragma unroll
    for (int i = 0; i < 4; ++i) {
#pragma unroll
        for (int r = 0; r < 4; ++r) {
            size_t row = brow + wr * 64 + i * 16 + g * 4 + r;
#pragma unroll
            for (int j = 0; j < 4; ++j) {
                size_t col = bcol + wc * 64 + j * 16 + lq;
                float v = acc[i][j][r];
                if (OUT_BF16) ((__bf16*)Cout)[row * N + col] = (__bf16)v;
                else          ((float*)Cout)[row * N + col] = v;
            }
        }
    }
}

// ---------------- V transpose: qkv V-part -> vt[(b*8+kh)*128+d][t] ----------------
__global__ __launch_bounds__(256)
void transpose_v(const __bf16* __restrict__ qkv, __bf16* __restrict__ vt) {
    constexpr int S = 2048, QKVN = 6144;
    __shared__ __bf16 tile[64][72];
    const int tt = blockIdx.x;
    const int yz = blockIdx.y;
    const int dh = yz & 1, bkh = yz >> 1;
    const int b = bkh >> 3, kh = bkh & 7;
    const int tid = threadIdx.x;
#pragma unroll
    for (int i = 0; i < 2; ++i) {
        int flat = i * 2048 + tid * 8;
        int r = flat >> 6, c0 = flat & 63;
        const __bf16* src = qkv + ((size_t)b * S + tt * 64 + r) * QKVN + 5120 + kh * 128 + dh * 64 + c0;
        *(bf16x8*)&tile[r][c0] = *(const bf16x8*)src;
    }
    __syncthreads();
#pragma unroll
    for (int i = 0; i < 2; ++i) {
        int flat = i * 2048 + tid * 8;
        int d = flat >> 6, t0 = flat & 63;
        bf16x8 pk;
#pragma unroll
        for (int e = 0; e < 8; ++e) pk[e] = tile[t0 + e][d];
        __bf16* dst = vt + ((size_t)(b * 8 + kh) * 128 + dh * 64 + d) * S + tt * 64 + t0;
        *(bf16x8*)dst = pk;
    }
}

// ---------------- flash attention v3 (causal, GQA) ----------------
// 64 q-rows/block (4 waves x 16 rows). KVBLK=64. Grid (bh=64, qtile=32), heavy qt first.
// Swapped QK^T: lane lq owns q-row lq; base-2 softmax, defer-max (T13), per-lane
// partial l (end-reduce). K staged in LDS (reg-prefetch, (row&15)<<4 swizzle);
// V read directly from global vt (L1/L2-resident). P via per-wave stride-152 LDS.
__global__ __launch_bounds__(256, 4)
void attn_kernel(const __bf16* __restrict__ qkv, const __bf16* __restrict__ vt,
                 __bf16* __restrict__ outb) {
    constexpr int S = 2048, D = 128, QKVN = 6144;
    const int qt = 31 - (int)blockIdx.y;                 // heavy blocks first
    const int bh = blockIdx.x;
    const int b = bh >> 5, h = bh & 31;
    const int kh = h >> 2;
    const int tid = threadIdx.x, lane = tid & 63, w = tid >> 6;
    const int g = lane >> 4, lq = lane & 15;

    __shared__ __bf16 Ks[64 * 128];          // [t][d], rows 256B, XOR (row&15)<<4
    __shared__ char   PsRaw[4][16 * 152];    // per-wave P rows, stride 152B

    const int wqmin = qt * 64 + w * 16;
    const int qg = wqmin + lq;

    // Q fragments (L2-resident)
    const __bf16* qrow = qkv + ((size_t)(b * S) + wqmin + lq) * QKVN + h * D;
    bf16x8 qf[4];
#pragma unroll
    for (int ks = 0; ks < 4; ++ks) qf[ks] = *(const bf16x8*)(qrow + ks * 32 + g * 8);

    const char* kbase = (const char*)qkv + ((size_t)(b * S) * QKVN + 4096 + kh * D) * 2;
    const char* vbase = (const char*)vt + ((size_t)(b * 8 + kh) * D * S) * 2;

    f32x4 acc[8] = {};
    float m_r = -1e30f, l_p = 0.f;
    const float scale2 = 0.12753102494f;     // (1/sqrt(128)) * log2(e)

    const int krow0 = tid >> 4;              // 0..15
    const int kcolb = (tid & 15) * 16;
    int4 pk[4];
#pragma unroll
    for (int is = 0; is < 4; ++is)
        pk[is] = *(const int4*)(kbase + (size_t)(is * 16 + krow0) * QKVN * 2 + kcolb);

    char* ps = &PsRaw[w][0];

    for (int kt = 0; kt <= qt; ++kt) {
        __syncthreads();                     // previous tile's reads done
#pragma unroll
        for (int is = 0; is < 4; ++is) {
            int row = is * 16 + krow0;
            *(int4*)((char*)Ks + row * 256 + (kcolb ^ ((row & 15) << 4))) = pk[is];
        }
        if (kt < qt) {                       // prefetch next K tile (hides under compute)
#pragma unroll
            for (int is = 0; is < 4; ++is)
                pk[is] = *(const int4*)(kbase + (size_t)((kt + 1) * 64 + is * 16 + krow0) * QKVN * 2 + kcolb);
        }
        __syncthreads();                     // tile ready

        // ---- QK^T (swapped): sc[tb][r] = S2[q=lq][t = kt*64 + tb*16 + g*4 + r]
        f32x4 sc[4];
        __builtin_amdgcn_s_setprio(1);
#pragma unroll
        for (int tb = 0; tb < 4; ++tb) {
            f32x4 s = {0.f, 0.f, 0.f, 0.f};
            const int trow = tb * 16 + lq;
            const int rsw = (trow & 15) << 4;
#pragma unroll
            for (int ks = 0; ks < 4; ++ks) {
                bf16x8 kf = *(const bf16x8*)((const char*)Ks + trow * 256 + ((ks * 64 + g * 16) ^ rsw));
                s = __builtin_amdgcn_mfma_f32_16x16x32_bf16(kf, qf[ks], s, 0, 0, 0);
            }
            sc[tb] = s;
        }
        __builtin_amdgcn_s_setprio(0);

        // ---- softmax (base-2, defer-max, per-lane partial l)
        float p[16];
        float rowmax = -1e30f;
        const bool domask = (kt == qt);
#pragma unroll
        for (int tb = 0; tb < 4; ++tb)
#pragma unroll
            for (int r = 0; r < 4; ++r) {
                float sv = sc[tb][r] * scale2;
                if (domask) {
                    int tg = kt * 64 + tb * 16 + g * 4 + r;
                    sv = (tg <= qg) ? sv : -1e30f;
                }
                p[tb * 4 + r] = sv;
                rowmax = fmaxf(rowmax, sv);
            }
        rowmax = fmaxf(rowmax, __shfl_xor(rowmax, 16));
        rowmax = fmaxf(rowmax, __shfl_xor(rowmax, 32));
        if (!__all(rowmax - m_r <= 11.0f)) { // rare rescale (T13, log2 domain)
            float m_new = fmaxf(m_r, rowmax);
            float alpha = exp2f(m_r - m_new);
            l_p *= alpha;
#pragma unroll
            for (int r = 0; r < 4; ++r) {
                float ar = __shfl(alpha, g * 4 + r);
#pragma unroll
                for (int nb = 0; nb < 8; ++nb) acc[nb][r] *= ar;
            }
            m_r = m_new;
        }
        float lsum = 0.f;
#pragma unroll
        for (int i = 0; i < 16; ++i) {
            float e = exp2f(p[i] - m_r);
            p[i] = e;
            lsum += e;
        }
        l_p += lsum;

        // ---- P -> per-wave LDS (row lq, byte col = 2*t)
#pragma unroll
        for (int tb = 0; tb < 4; ++tb) {
            bf16x4 pkv;
#pragma unroll
            for (int r = 0; r < 4; ++r) pkv[r] = (__bf16)p[tb * 4 + r];
            *(bf16x4*)(ps + lq * 152 + tb * 32 + g * 8) = pkv;
        }

        // ---- PV: A = P (from Ps), B = V^T rows straight from global (L1/L2)
        __builtin_amdgcn_s_setprio(1);
#pragma unroll
        for (int ks = 0; ks < 2; ++ks) {
            bf16x8 pa = *(const bf16x8*)(ps + lq * 152 + ks * 64 + g * 16);
#pragma unroll
            for (int nb = 0; nb < 8; ++nb) {
                int d = nb * 16 + lq;
                bf16x8 vf = *(const bf16x8*)(vbase + ((size_t)d * S + kt * 64 + ks * 32 + g * 8) * 2);
                acc[nb] = __builtin_amdgcn_mfma_f32_16x16x32_bf16(pa, vf, acc[nb], 0, 0, 0);
            }
        }
        __builtin_amdgcn_s_setprio(0);
    }

    // ---- epilogue: reduce l across g-groups, normalize, store
    l_p += __shfl_xor(l_p, 16);
    l_p += __shfl_xor(l_p, 32);
    float rl = 1.f / l_p;
#pragma unroll
    for (int r = 0; r < 4; ++r) {
        float rr = __shfl(rl, g * 4 + r);
        size_t row = (size_t)(b * S) + wqmin + g * 4 + r;
        __bf16* orow = outb + row * 4096 + h * D;
#pragma unroll
        for (int nb = 0; nb < 8; ++nb)
            orow[nb * 16 + lq] = (__bf16)(acc[nb][r] * rr);
    }
}

// ---------------- launch ----------------
extern "C" void kernel_launch(void* const* d_in, const int* in_sizes, int n_in,
                              void* d_out, int out_size, void* d_ws, size_t ws_size,
                              hipStream_t stream) {
    (void)in_sizes; (void)n_in; (void)out_size; (void)ws_size;
    const float* q       = (const float*)d_in[0];
    const float* w_qkv   = (const float*)d_in[1];
    const float* w_dense = (const float*)d_in[2];
    float* out = (float*)d_out;
    char* ws = (char*)d_ws;

    __bf16* qbf      = (__bf16*)(ws);
    __bf16* wqkvbf   = (__bf16*)(ws + 33554432ULL);
    __bf16* wdensebf = (__bf16*)(ws + 83886080ULL);
    __bf16* qkvbf    = (__bf16*)(ws + 117440512ULL);
    __bf16* vtbf     = (__bf16*)(ws + 167772160ULL);
    __bf16* attnbf   = (__bf16*)(ws + 176160768ULL);

    cast_f32_bf16<<<8192, 256, 0, stream>>>(q, qbf, 2097152);
    cast_f32_bf16<<<12288, 256, 0, stream>>>(w_qkv, wqkvbf, 3145728);
    cast_f32_bf16<<<8192, 256, 0, stream>>>(w_dense, wdensebf, 2097152);

    gemm_bt<1><<<dim3(48, 32), 256, 0, stream>>>(qbf, wqkvbf, (void*)qkvbf, 4096, 6144, 4096);
    transpose_v<<<dim3(32, 32), 256, 0, stream>>>(qkvbf, vtbf);
    attn_kernel<<<dim3(64, 32), 256, 0, stream>>>(qkvbf, vtbf, attnbf);
    gemm_bt<0><<<dim3(32, 32), 256, 0, stream>>>(attnbf, wdensebf, (void*)out, 4096, 4096, 4096);
}